// Round 11
// baseline (465.536 us; speedup 1.0000x reference)
//
#include <hip/hip_runtime.h>
#include <hip/hip_bf16.h>
#include <cstdint>
#include <cstddef>

typedef unsigned short u16;
typedef uint32_t u32;
typedef __attribute__((ext_vector_type(4))) float f32x4;
typedef __attribute__((ext_vector_type(8))) short bf16x8;

#define NTOK 8192
#define DIM  1024
#define HID  2048
#define NEXP 8
#define MAXT1 72     // 256-row tiles: sum ceil(n_e/256) <= 64+8
#define MAXT2 136    // 128-row tiles: sum ceil(n_e/128) <= 128+8

// async global->LDS, 16B per lane; LDS dest is wave-uniform base + lane*16
#define GLD16(g, l) __builtin_amdgcn_global_load_lds( \
    (const __attribute__((address_space(1))) void*)(g), \
    (__attribute__((address_space(3))) void*)(l), 16, 0, 0)

#define WAITV(n) asm volatile("s_waitcnt vmcnt(" #n ")" ::: "memory")

__device__ __forceinline__ u16 f2bf(float f) {
  __hip_bfloat16 h = __float2bfloat16(f);
  return __builtin_bit_cast(u16, h);
}
__device__ __forceinline__ float bf2f(short s) {
  u32 u = ((u32)(u16)s) << 16;
  return __builtin_bit_cast(float, u);
}

// swizzled LDS fragment address: row stride 64 u16 (128B), chunk = 16B unit.
// physical slot = chunk ^ (row&7); stage side pre-permutes the global source.
__device__ __forceinline__ const bf16x8* lds_frag(const u16* base, int row, int chunk) {
  return (const bf16x8*)(base + row * 64 + ((chunk ^ (row & 7)) << 3));
}

// ---------------- fp32 -> bf16 conversion: W1,W2,W3 in ONE launch ----------
// MUST run standalone and FIRST: the ~40us of gating/hist/scan/scatter
// between this kernel and gemm1 drains its 100MB of L2/LLC writebacks
// (R8 measured: fusing prep closer to gemm1 cost gemm1 196->219us).
__global__ __launch_bounds__(256) void convert3_kernel(
    const float4* __restrict__ s0, const float4* __restrict__ s1,
    const float4* __restrict__ s2, ushort4* __restrict__ d0,
    ushort4* __restrict__ d1, ushort4* __restrict__ d2) {
  const int n4 = 1 << 22;
  int stride = gridDim.x * blockDim.x;
  for (int i = blockIdx.x * blockDim.x + threadIdx.x; i < 3 * n4; i += stride) {
    int t = i >> 22, off = i & (n4 - 1);
    const float4* s = (t == 0) ? s0 : (t == 1) ? s1 : s2;
    ushort4* d      = (t == 0) ? d0 : (t == 1) ? d1 : d2;
    float4 v = s[off];
    ushort4 o;
    o.x = f2bf(v.x); o.y = f2bf(v.y); o.z = f2bf(v.z); o.w = f2bf(v.w);
    d[off] = o;
  }
}

// ---------------- fp32 gating + fused x->bf16: ONE WAVE PER TOKEN ---------
// NO count atomics here: R9 measured that 16384 wave-leader atomics on 8
// cache lines serialize (~25us); the LDS-aggregated hist pass is cheaper.
__global__ __launch_bounds__(256) void gating_kernel(
    const float4* __restrict__ x4, const float4* __restrict__ Wg4,
    int* __restrict__ gate_idx, float* __restrict__ gate_prob,
    u16* __restrict__ Xb) {
  int tid = threadIdx.x, w = tid >> 6, l = tid & 63;
  int t = blockIdx.x * 4 + w;

  float4 xv[4];
#pragma unroll
  for (int j = 0; j < 4; ++j)
    xv[j] = x4[(size_t)t * 256 + l + 64 * j];

  float acc[NEXP];
#pragma unroll
  for (int e = 0; e < NEXP; ++e) acc[e] = 0.f;
#pragma unroll
  for (int e = 0; e < NEXP; ++e)
#pragma unroll
    for (int j = 0; j < 4; ++j) {
      float4 wv = Wg4[e * 256 + l + 64 * j];
      acc[e] += xv[j].x * wv.x + xv[j].y * wv.y + xv[j].z * wv.z + xv[j].w * wv.w;
    }

  // fused bf16 conversion of x (coalesced ushort4 stores)
#pragma unroll
  for (int j = 0; j < 4; ++j) {
    ushort4 o;
    o.x = f2bf(xv[j].x); o.y = f2bf(xv[j].y);
    o.z = f2bf(xv[j].z); o.w = f2bf(xv[j].w);
    *(ushort4*)&Xb[(size_t)t * DIM + (l + 64 * j) * 4] = o;
  }

#pragma unroll
  for (int off = 32; off >= 1; off >>= 1)
#pragma unroll
    for (int e = 0; e < NEXP; ++e)
      acc[e] += __shfl_xor(acc[e], off);

  if (l == 0) {
    float best = -1e30f, sec = -1e30f;
    int bi = 0, si = 0;
#pragma unroll
    for (int e = 0; e < NEXP; ++e) {
      float s = acc[e];
      if (s > best)      { sec = best; si = bi; best = s; bi = e; }
      else if (s > sec)  { sec = s; si = e; }
    }
    float e1  = __expf(sec - best);
    float inv = 1.f / (1.f + e1);
    gate_idx[t * 2]      = bi;
    gate_idx[t * 2 + 1]  = si;
    gate_prob[t * 2]     = inv;
    gate_prob[t * 2 + 1] = e1 * inv;
  }
}

// ---------------- histogram: LDS-aggregated, 8 atomics/block ----------------
__global__ __launch_bounds__(256) void hist_kernel(
    const int* __restrict__ gate_idx, int* __restrict__ counts) {
  __shared__ int h[NEXP];
  int tid = threadIdx.x;
  if (tid < NEXP) h[tid] = 0;
  __syncthreads();
  int i = blockIdx.x * 256 + tid;      // grid 64 x 256 covers 16384 entries
  atomicAdd(&h[gate_idx[i]], 1);
  __syncthreads();
  if (tid < NEXP) atomicAdd(&counts[tid], h[tid]);
}

// ---------------- scan + tile tables ----------------
__global__ void scan_kernel(const int* __restrict__ counts,
                            int* __restrict__ offs, int* __restrict__ cursors,
                            int* __restrict__ tileE1, int* __restrict__ tileRow1,
                            int* __restrict__ nt1,
                            int* __restrict__ tileE2, int* __restrict__ tileRow2,
                            int* __restrict__ nt2) {
  if (threadIdx.x == 0 && blockIdx.x == 0) {
    int s = 0;
    for (int e = 0; e < NEXP; ++e) { offs[e] = s; cursors[e] = s; s += counts[e]; }
    int n1 = 0, n2 = 0;
    for (int e = 0; e < NEXP; ++e) {
      for (int r = 0; r < counts[e]; r += 256) { tileE1[n1] = e; tileRow1[n1] = r; ++n1; }
      for (int r = 0; r < counts[e]; r += 128) { tileE2[n2] = e; tileRow2[n2] = r; ++n2; }
    }
    *nt1 = n1; *nt2 = n2;
  }
}

// ---------------- scatter: LDS local cursors, 8 global atomics/block -------
__global__ __launch_bounds__(256) void scatter_kernel(
    const int* __restrict__ gate_idx, int* __restrict__ cursors,
    int* __restrict__ list, int* __restrict__ pos_of) {
  __shared__ int lc[NEXP];
  __shared__ int lbase[NEXP];
  int tid = threadIdx.x;
  if (tid < NEXP) lc[tid] = 0;
  __syncthreads();
  int i = blockIdx.x * 256 + tid;      // grid 64 x 256
  int e = gate_idx[i];
  int lp = atomicAdd(&lc[e], 1);
  __syncthreads();
  if (tid < NEXP) lbase[tid] = atomicAdd(&cursors[tid], lc[tid]);
  __syncthreads();
  int pos = lbase[e] + lp;
  list[pos] = i;
  pos_of[i] = pos;
}

// ---------------- GEMM1: hidden = silu(X.W1^T) * (X.W2^T) ----------------
// R11: A (gathered X rows) loaded DIRECTLY from global into MFMA fragments
// (X is L2-resident after the tn-fastest swizzle: ~2MB/XCD), B1/B2 staged in
// LDS as before. LDS traffic per block-K-tile: 288KB -> 160KB (-44%); the
// measured budget showed LDS b128 throughput (~85 B/cyc) was the largest
// single term (~3400 of ~6500 cyc). Stage = 4 loads/wave -> WAITV(4): at
// iter-top only B(kt+1) can be outstanding (A(kt-1) was consumed by MFMA,
// hence complete). A fragment (canonical 16x16x32 layout, no swizzle):
// lane reads 16B at X[token(row)]*DIM + kt*64 + ks*32 + (l>>4)*8.
// Refuted alternatives (do NOT redo): phase-split (R1/R2), stage-early lgkm
// drain (R5), single-buffer (R7), 128x64 tile (R4), launch_bounds(512,4)
// spill (R6).
__global__ __launch_bounds__(512, 2) void gemm1_kernel(
    const u16* __restrict__ Xb, const u16* __restrict__ W1b,
    const u16* __restrict__ W2b, const int* __restrict__ list,
    const int* __restrict__ offs, const int* __restrict__ counts,
    const int* __restrict__ tileE, const int* __restrict__ tileRow,
    const int* __restrict__ n_tiles, u16* __restrict__ hidden) {
  int flat = blockIdx.x + MAXT1 * blockIdx.y;
  int nf = (flat & 7) * (MAXT1 * (HID / 128) / 8) + (flat >> 3);
  int bx = nf >> 4;          // row-tile: SLOW index (L2 keeps its X rows)
  int tn = nf & 15;          // col-tile: FAST index
  if (bx >= *n_tiles) return;
  int e = tileE[bx], row0 = tileRow[bx];
  int n_e = counts[e], off_e = offs[e];
  __shared__ u16 B1s[2][128 * 64];  // 32KB
  __shared__ u16 B2s[2][128 * 64];  // 32KB  (A no longer staged: 64KB LDS)
  int tid = threadIdx.x, w = tid >> 6, l = tid & 63;
  const u16* W1e = W1b + (size_t)e * HID * DIM;
  const u16* W2e = W2b + (size_t)e * HID * DIM;

  int wm = w >> 1, wn = w & 1;

  // per-lane A fragment base offsets (u16 units): row = wm*64 + mi*16 + (l&15)
  u32 aoff[4];
#pragma unroll
  for (int mi = 0; mi < 4; ++mi) {
    int idx = row0 + wm * 64 + mi * 16 + (l & 15);
    int entry = list[off_e + (idx < n_e ? idx : 0)];
    aoff[mi] = (u32)(entry >> 1) * DIM + (l >> 4) * 8;
  }

  int schunk = ((l & 7) ^ (l >> 3)) * 8;
  u32 offB[2];
#pragma unroll
  for (int j = 0; j < 2; ++j) {
    int r = w * 16 + j * 8 + (l >> 3);
    offB[j] = (u32)(tn * 128 + r) * DIM + schunk;
  }

#define STAGEB(buf, kt) do { u32 kof_ = (u32)(kt) * 64;                        \
    _Pragma("unroll")                                                          \
    for (int j = 0; j < 2; ++j) {                                              \
      GLD16(W1e + offB[j] + kof_, &B1s[buf][w * 1024 + j * 512]);              \
      GLD16(W2e + offB[j] + kof_, &B2s[buf][w * 1024 + j * 512]);              \
    } } while (0)

  f32x4 acc1[4][4], acc2[4][4];
#pragma unroll
  for (int mi = 0; mi < 4; ++mi)
#pragma unroll
    for (int ni = 0; ni < 4; ++ni) {
      acc1[mi][ni] = (f32x4){0.f, 0.f, 0.f, 0.f};
      acc2[mi][ni] = (f32x4){0.f, 0.f, 0.f, 0.f};
    }

  const int NKT = DIM / 64;
  STAGEB(0, 0);
  STAGEB(1, 1);
  for (int kt = 0; kt < NKT; ++kt) {
    // drain to 4: leaves only B(kt+1) in flight -> B(kt) landed.
    // A(kt-1) loads were consumed by MFMA (compiler vmcnt) -> complete.
    if (kt < NKT - 1) { WAITV(4); } else { WAITV(0); }
    __builtin_amdgcn_s_barrier();
    int cur = kt & 1;
    const u16* B1b = B1s[cur];
    const u16* B2b = B2s[cur];

    // A fragments direct from global (L2/L1-resident X); issued first so
    // their latency hides under the 16 ds_reads + early MFMAs below.
    bf16x8 a[4][2];
#pragma unroll
    for (int mi = 0; mi < 4; ++mi)
#pragma unroll
      for (int ks = 0; ks < 2; ++ks)
        a[mi][ks] = *(const bf16x8*)(Xb + aoff[mi] + (u32)kt * 64 + ks * 32);

#pragma unroll
    for (int ks = 0; ks < 2; ++ks) {
      bf16x8 b1[4], b2[4];
#pragma unroll
      for (int ni = 0; ni < 4; ++ni) {
        b1[ni] = *lds_frag(B1b, wn * 64 + ni * 16 + (l & 15), ks * 4 + (l >> 4));
        b2[ni] = *lds_frag(B2b, wn * 64 + ni * 16 + (l & 15), ks * 4 + (l >> 4));
      }
#pragma unroll
      for (int mi = 0; mi < 4; ++mi)
#pragma unroll
        for (int ni = 0; ni < 4; ++ni) {
          acc1[mi][ni] = __builtin_amdgcn_mfma_f32_16x16x32_bf16(a[mi][ks], b1[ni], acc1[mi][ni], 0, 0, 0);
          acc2[mi][ni] = __builtin_amdgcn_mfma_f32_16x16x32_bf16(a[mi][ks], b2[ni], acc2[mi][ni], 0, 0, 0);
        }
    }
    asm volatile("" ::: "memory");
    __builtin_amdgcn_s_barrier();
    if (kt + 2 < NKT) STAGEB(cur, kt + 2);
  }

#pragma unroll
  for (int mi = 0; mi < 4; ++mi) {
#pragma unroll
    for (int i = 0; i < 4; ++i) {
      int m_loc = wm * 64 + mi * 16 + (l >> 4) * 4 + i;
      int idx = row0 + m_loc;
      if (idx < n_e) {
        size_t pos = (size_t)(off_e + idx);
#pragma unroll
        for (int ni = 0; ni < 4; ++ni) {
          int h_loc = tn * 128 + wn * 64 + ni * 16 + (l & 15);
          float h1 = acc1[mi][ni][i];
          float h2 = acc2[mi][ni][i];
          float hv = h1 / (1.f + __expf(-h1)) * h2;
          hidden[pos * HID + h_loc] = f2bf(hv);
        }
      }
    }
  }
#undef STAGEB
}

// ---------------- GEMM2: eout = hidden . W3^T (unscaled bf16) ----------------
// R3-proven config, UNCHANGED (attribution isolation). tn FASTEST swizzle.
__global__ __launch_bounds__(256, 2) void gemm2_kernel(
    const u16* __restrict__ hidden, const u16* __restrict__ W3b,
    const int* __restrict__ offs, const int* __restrict__ counts,
    const int* __restrict__ tileE, const int* __restrict__ tileRow,
    const int* __restrict__ n_tiles, u16* __restrict__ eout) {
  int flat = blockIdx.x + MAXT2 * blockIdx.y;
  int nf = (flat & 7) * (MAXT2 * (DIM / 128) / 8) + (flat >> 3);
  int bx = nf >> 3;          // row-tile: SLOW index
  int tn = nf & 7;           // col-tile: FAST index
  if (bx >= *n_tiles) return;
  int e = tileE[bx], row0 = tileRow[bx];
  int n_e = counts[e], off_e = offs[e];
  __shared__ u16 As[2][128 * 64];
  __shared__ u16 Bs[2][128 * 64];
  int tid = threadIdx.x, w = tid >> 6, l = tid & 63;
  const u16* W3e = W3b + (size_t)e * DIM * HID;

  int schunk = ((l & 7) ^ (l >> 3)) * 8;
  u32 offA[4], offB[4];
#pragma unroll
  for (int j = 0; j < 4; ++j) {
    int r = w * 32 + j * 8 + (l >> 3);
    int idx = row0 + r;
    int pos = off_e + (idx < n_e ? idx : 0);
    offA[j] = (u32)pos * HID + schunk;
    offB[j] = (u32)(tn * 128 + r) * HID + schunk;
  }

#define STAGE2(buf, kt) do { u32 kof_ = (u32)(kt) * 64;                        \
    _Pragma("unroll")                                                          \
    for (int j = 0; j < 4; ++j) {                                              \
      GLD16(hidden + offA[j] + kof_, &As[buf][w * 2048 + j * 512]);            \
      GLD16(W3e    + offB[j] + kof_, &Bs[buf][w * 2048 + j * 512]);            \
    } } while (0)

  f32x4 acc[4][4];
#pragma unroll
  for (int mi = 0; mi < 4; ++mi)
#pragma unroll
    for (int ni = 0; ni < 4; ++ni) acc[mi][ni] = (f32x4){0.f, 0.f, 0.f, 0.f};
  int wm = w >> 1, wn = w & 1;

  STAGE2(0, 0);
  STAGE2(1, 1);
  for (int kt = 0; kt < HID / 64; ++kt) {
    if (kt < HID / 64 - 1) { WAITV(8); } else { WAITV(0); }
    __builtin_amdgcn_s_barrier();
    int cur = kt & 1;
    const u16* Ab = As[cur];
    const u16* Bb = Bs[cur];
#pragma unroll
    for (int ks = 0; ks < 2; ++ks) {
      bf16x8 a[4], b[4];
#pragma unroll
      for (int mi = 0; mi < 4; ++mi)
        a[mi] = *lds_frag(Ab, wm * 64 + mi * 16 + (l & 15), ks * 4 + (l >> 4));
#pragma unroll
      for (int ni = 0; ni < 4; ++ni)
        b[ni] = *lds_frag(Bb, wn * 64 + ni * 16 + (l & 15), ks * 4 + (l >> 4));
#pragma unroll
      for (int mi = 0; mi < 4; ++mi)
#pragma unroll
        for (int ni = 0; ni < 4; ++ni)
          acc[mi][ni] = __builtin_amdgcn_mfma_f32_16x16x32_bf16(a[mi], b[ni], acc[mi][ni], 0, 0, 0);
    }
    asm volatile("" ::: "memory");
    __builtin_amdgcn_s_barrier();
    if (kt + 2 < HID / 64) STAGE2(cur, kt + 2);
  }

#pragma unroll
  for (int mi = 0; mi < 4; ++mi) {
#pragma unroll
    for (int i = 0; i < 4; ++i) {
      int m_loc = wm * 64 + mi * 16 + (l >> 4) * 4 + i;
      int idx = row0 + m_loc;
      if (idx < n_e) {
        size_t pos = (size_t)(off_e + idx);
#pragma unroll
        for (int ni = 0; ni < 4; ++ni) {
          int d_loc = tn * 128 + wn * 64 + ni * 16 + (l & 15);
          eout[pos * DIM + d_loc] = f2bf(acc[mi][ni][i]);
        }
      }
    }
  }
#undef STAGE2
}

// ---------------- combine: out[t] = p0*eout[pos0] + p1*eout[pos1] ----------
__global__ __launch_bounds__(256) void combine_kernel(
    const u16* __restrict__ eout, const int* __restrict__ pos_of,
    const float* __restrict__ gate_prob, float* __restrict__ out) {
  int gid = blockIdx.x * 256 + threadIdx.x;   // NTOK*128 threads
  int t = gid >> 7, dq = (gid & 127) * 8;
  int p0 = pos_of[t * 2], p1 = pos_of[t * 2 + 1];
  float w0 = gate_prob[t * 2], w1 = gate_prob[t * 2 + 1];
  bf16x8 e0 = *(const bf16x8*)&eout[(size_t)p0 * DIM + dq];
  bf16x8 e1 = *(const bf16x8*)&eout[(size_t)p1 * DIM + dq];
  float4 o0, o1;
  o0.x = w0 * bf2f(e0[0]) + w1 * bf2f(e1[0]);
  o0.y = w0 * bf2f(e0[1]) + w1 * bf2f(e1[1]);
  o0.z = w0 * bf2f(e0[2]) + w1 * bf2f(e1[2]);
  o0.w = w0 * bf2f(e0[3]) + w1 * bf2f(e1[3]);
  o1.x = w0 * bf2f(e0[4]) + w1 * bf2f(e1[4]);
  o1.y = w0 * bf2f(e0[5]) + w1 * bf2f(e1[5]);
  o1.z = w0 * bf2f(e0[6]) + w1 * bf2f(e1[6]);
  o1.w = w0 * bf2f(e0[7]) + w1 * bf2f(e1[7]);
  float4* op = (float4*)&out[(size_t)t * DIM + dq];
  op[0] = o0; op[1] = o1;
}

// ---------------- launch ----------------
extern "C" void kernel_launch(void* const* d_in, const int* in_sizes, int n_in,
                              void* d_out, int out_size, void* d_ws, size_t ws_size,
                              hipStream_t stream) {
  const float* x  = (const float*)d_in[0];
  const float* Wg = (const float*)d_in[1];
  const float* W1 = (const float*)d_in[2];
  const float* W2 = (const float*)d_in[3];
  const float* W3 = (const float*)d_in[4];
  float* out = (float*)d_out;

  char* wsb = (char*)d_ws;
  int*   counts    = (int*)(wsb + 0);
  int*   cursors   = (int*)(wsb + 64);
  int*   offs      = (int*)(wsb + 128);
  int*   nt1       = (int*)(wsb + 192);
  int*   nt2       = (int*)(wsb + 196);
  int*   tileE1    = (int*)(wsb + 512);
  int*   tileRow1  = (int*)(wsb + 1024);
  int*   tileE2    = (int*)(wsb + 1536);
  int*   tileRow2  = (int*)(wsb + 2560);
  int*   gate_idx  = (int*)(wsb + 4096);
  float* gate_prob = (float*)(wsb + 4096 + 65536);
  int*   pos_of    = (int*)(wsb + 4096 + 2 * 65536);
  int*   list      = (int*)(wsb + 4096 + 3 * 65536);
  u16* Xb     = (u16*)(wsb + (1 << 20));
  u16* W1b    = Xb  + (size_t)NTOK * DIM;
  u16* W2b    = W1b + (size_t)NEXP * HID * DIM;
  u16* W3b    = W2b + (size_t)NEXP * HID * DIM;
  u16* hidden = W3b + (size_t)NEXP * DIM * HID;   // [2*NTOK][HID]
  u16* eout   = W1b;   // W1b/W2b dead after gemm1

  hipMemsetAsync(wsb, 0, 256, stream);

  convert3_kernel<<<4096, 256, 0, stream>>>(
      (const float4*)W1, (const float4*)W2, (const float4*)W3,
      (ushort4*)W1b, (ushort4*)W2b, (ushort4*)W3b);

  gating_kernel<<<NTOK / 4, 256, 0, stream>>>(
      (const float4*)x, (const float4*)Wg, gate_idx, gate_prob, Xb);
  hist_kernel<<<NTOK * 2 / 256, 256, 0, stream>>>(gate_idx, counts);
  scan_kernel<<<1, 64, 0, stream>>>(counts, offs, cursors,
                                    tileE1, tileRow1, nt1, tileE2, tileRow2, nt2);
  scatter_kernel<<<NTOK * 2 / 256, 256, 0, stream>>>(gate_idx, cursors, list, pos_of);

  gemm1_kernel<<<dim3(MAXT1, HID / 128), 512, 0, stream>>>(
      Xb, W1b, W2b, list, offs, counts, tileE1, tileRow1, nt1, hidden);
  gemm2_kernel<<<dim3(MAXT2, DIM / 128), 256, 0, stream>>>(
      hidden, W3b, offs, counts, tileE2, tileRow2, nt2, eout);
  combine_kernel<<<NTOK * 128 / 256, 256, 0, stream>>>(eout, pos_of, gate_prob, out);
}

// Round 12
// 359.867 us; speedup vs baseline: 1.2936x; 1.2936x over previous
//
#include <hip/hip_runtime.h>
#include <hip/hip_bf16.h>
#include <cstdint>
#include <cstddef>

typedef unsigned short u16;
typedef uint32_t u32;
typedef __attribute__((ext_vector_type(4))) float f32x4;
typedef __attribute__((ext_vector_type(8))) short bf16x8;

#define NTOK 8192
#define DIM  1024
#define HID  2048
#define NEXP 8
#define MAXT1 72     // 256-row tiles: sum ceil(n_e/256) <= 64+8
#define MAXT2 136    // 128-row tiles: sum ceil(n_e/128) <= 128+8

// async global->LDS, 16B per lane; LDS dest is wave-uniform base + lane*16
#define GLD16(g, l) __builtin_amdgcn_global_load_lds( \
    (const __attribute__((address_space(1))) void*)(g), \
    (__attribute__((address_space(3))) void*)(l), 16, 0, 0)

#define WAITV(n) asm volatile("s_waitcnt vmcnt(" #n ")" ::: "memory")

__device__ __forceinline__ u16 f2bf(float f) {
  __hip_bfloat16 h = __float2bfloat16(f);
  return __builtin_bit_cast(u16, h);
}
__device__ __forceinline__ float bf2f(short s) {
  u32 u = ((u32)(u16)s) << 16;
  return __builtin_bit_cast(float, u);
}

// swizzled LDS fragment address: row stride 64 u16 (128B), chunk = 16B unit.
// physical slot = chunk ^ (row&7); stage side pre-permutes the global source.
__device__ __forceinline__ const bf16x8* lds_frag(const u16* base, int row, int chunk) {
  return (const bf16x8*)(base + row * 64 + ((chunk ^ (row & 7)) << 3));
}

// ---------------- fp32 -> bf16 conversion: W1,W2,W3 in ONE launch ----------
// MUST run standalone and FIRST: the ~40us of gating/hist/scan/scatter
// between this kernel and gemm1 drains its 100MB of L2/LLC writebacks
// (R8 measured: fusing prep closer to gemm1 cost gemm1 196->219us).
__global__ __launch_bounds__(256) void convert3_kernel(
    const float4* __restrict__ s0, const float4* __restrict__ s1,
    const float4* __restrict__ s2, ushort4* __restrict__ d0,
    ushort4* __restrict__ d1, ushort4* __restrict__ d2) {
  const int n4 = 1 << 22;
  int stride = gridDim.x * blockDim.x;
  for (int i = blockIdx.x * blockDim.x + threadIdx.x; i < 3 * n4; i += stride) {
    int t = i >> 22, off = i & (n4 - 1);
    const float4* s = (t == 0) ? s0 : (t == 1) ? s1 : s2;
    ushort4* d      = (t == 0) ? d0 : (t == 1) ? d1 : d2;
    float4 v = s[off];
    ushort4 o;
    o.x = f2bf(v.x); o.y = f2bf(v.y); o.z = f2bf(v.z); o.w = f2bf(v.w);
    d[off] = o;
  }
}

// ---------------- fp32 gating + fused x->bf16: ONE WAVE PER TOKEN ---------
// NO count atomics here: R9 measured that 16384 wave-leader atomics on 8
// cache lines serialize (~25us); the LDS-aggregated hist pass is cheaper.
__global__ __launch_bounds__(256) void gating_kernel(
    const float4* __restrict__ x4, const float4* __restrict__ Wg4,
    int* __restrict__ gate_idx, float* __restrict__ gate_prob,
    u16* __restrict__ Xb) {
  int tid = threadIdx.x, w = tid >> 6, l = tid & 63;
  int t = blockIdx.x * 4 + w;

  float4 xv[4];
#pragma unroll
  for (int j = 0; j < 4; ++j)
    xv[j] = x4[(size_t)t * 256 + l + 64 * j];

  float acc[NEXP];
#pragma unroll
  for (int e = 0; e < NEXP; ++e) acc[e] = 0.f;
#pragma unroll
  for (int e = 0; e < NEXP; ++e)
#pragma unroll
    for (int j = 0; j < 4; ++j) {
      float4 wv = Wg4[e * 256 + l + 64 * j];
      acc[e] += xv[j].x * wv.x + xv[j].y * wv.y + xv[j].z * wv.z + xv[j].w * wv.w;
    }

  // fused bf16 conversion of x (coalesced ushort4 stores)
#pragma unroll
  for (int j = 0; j < 4; ++j) {
    ushort4 o;
    o.x = f2bf(xv[j].x); o.y = f2bf(xv[j].y);
    o.z = f2bf(xv[j].z); o.w = f2bf(xv[j].w);
    *(ushort4*)&Xb[(size_t)t * DIM + (l + 64 * j) * 4] = o;
  }

#pragma unroll
  for (int off = 32; off >= 1; off >>= 1)
#pragma unroll
    for (int e = 0; e < NEXP; ++e)
      acc[e] += __shfl_xor(acc[e], off);

  if (l == 0) {
    float best = -1e30f, sec = -1e30f;
    int bi = 0, si = 0;
#pragma unroll
    for (int e = 0; e < NEXP; ++e) {
      float s = acc[e];
      if (s > best)      { sec = best; si = bi; best = s; bi = e; }
      else if (s > sec)  { sec = s; si = e; }
    }
    float e1  = __expf(sec - best);
    float inv = 1.f / (1.f + e1);
    gate_idx[t * 2]      = bi;
    gate_idx[t * 2 + 1]  = si;
    gate_prob[t * 2]     = inv;
    gate_prob[t * 2 + 1] = e1 * inv;
  }
}

// ---------------- histogram: LDS-aggregated, 8 atomics/block ----------------
__global__ __launch_bounds__(256) void hist_kernel(
    const int* __restrict__ gate_idx, int* __restrict__ counts) {
  __shared__ int h[NEXP];
  int tid = threadIdx.x;
  if (tid < NEXP) h[tid] = 0;
  __syncthreads();
  int i = blockIdx.x * 256 + tid;      // grid 64 x 256 covers 16384 entries
  atomicAdd(&h[gate_idx[i]], 1);
  __syncthreads();
  if (tid < NEXP) atomicAdd(&counts[tid], h[tid]);
}

// ---------------- scan + tile tables ----------------
__global__ void scan_kernel(const int* __restrict__ counts,
                            int* __restrict__ offs, int* __restrict__ cursors,
                            int* __restrict__ tileE1, int* __restrict__ tileRow1,
                            int* __restrict__ nt1,
                            int* __restrict__ tileE2, int* __restrict__ tileRow2,
                            int* __restrict__ nt2) {
  if (threadIdx.x == 0 && blockIdx.x == 0) {
    int s = 0;
    for (int e = 0; e < NEXP; ++e) { offs[e] = s; cursors[e] = s; s += counts[e]; }
    int n1 = 0, n2 = 0;
    for (int e = 0; e < NEXP; ++e) {
      for (int r = 0; r < counts[e]; r += 256) { tileE1[n1] = e; tileRow1[n1] = r; ++n1; }
      for (int r = 0; r < counts[e]; r += 128) { tileE2[n2] = e; tileRow2[n2] = r; ++n2; }
    }
    *nt1 = n1; *nt2 = n2;
  }
}

// ---------------- scatter: LDS local cursors, 8 global atomics/block -------
__global__ __launch_bounds__(256) void scatter_kernel(
    const int* __restrict__ gate_idx, int* __restrict__ cursors,
    int* __restrict__ list, int* __restrict__ pos_of) {
  __shared__ int lc[NEXP];
  __shared__ int lbase[NEXP];
  int tid = threadIdx.x;
  if (tid < NEXP) lc[tid] = 0;
  __syncthreads();
  int i = blockIdx.x * 256 + tid;      // grid 64 x 256
  int e = gate_idx[i];
  int lp = atomicAdd(&lc[e], 1);
  __syncthreads();
  if (tid < NEXP) lbase[tid] = atomicAdd(&cursors[tid], lc[tid]);
  __syncthreads();
  int pos = lbase[e] + lp;
  list[pos] = i;
  pos_of[i] = pos;
}

// ---------------- GEMM1: hidden = silu(X.W1^T) * (X.W2^T) ----------------
// Session-optimal config (196us, FETCH 184MB, 701 TF): 8 waves (512 thr),
// tile 256 rows x 128 h, BK=64, 128KB dbuf LDS, counted-vmcnt 2-phase loop,
// XCD-chunked swizzle with tn FASTEST (each XCD keeps ~2 row-tiles of X
// L2-resident across all 16 col strips). Refuted alternatives (do NOT redo):
// phase-split (R1/R2: -5..-9%), stage-early+lgkm(0) (R5: -9%), single-buffer
// (R7: -17%), 128x64 tile (R4: +0, worse FETCH), launch_bounds (512,4)
// (R6: VGPR cap 128 -> acc spill, 3.7GB scratch), A-direct-from-global
// (R11: -52%, L2 latency exposed serially before each MFMA cluster).
__global__ __launch_bounds__(512, 2) void gemm1_kernel(
    const u16* __restrict__ Xb, const u16* __restrict__ W1b,
    const u16* __restrict__ W2b, const int* __restrict__ list,
    const int* __restrict__ offs, const int* __restrict__ counts,
    const int* __restrict__ tileE, const int* __restrict__ tileRow,
    const int* __restrict__ n_tiles, u16* __restrict__ hidden) {
  int flat = blockIdx.x + MAXT1 * blockIdx.y;
  int nf = (flat & 7) * (MAXT1 * (HID / 128) / 8) + (flat >> 3);
  int bx = nf >> 4;          // row-tile: SLOW index (L2 keeps its X rows)
  int tn = nf & 15;          // col-tile: FAST index
  if (bx >= *n_tiles) return;
  int e = tileE[bx], row0 = tileRow[bx];
  int n_e = counts[e], off_e = offs[e];
  __shared__ u16 As[2][256 * 64];   // 64KB
  __shared__ u16 B1s[2][128 * 64];  // 32KB
  __shared__ u16 B2s[2][128 * 64];  // 32KB
  int tid = threadIdx.x, w = tid >> 6, l = tid & 63;
  const u16* W1e = W1b + (size_t)e * HID * DIM;
  const u16* W2e = W2b + (size_t)e * HID * DIM;

  int schunk = ((l & 7) ^ (l >> 3)) * 8;
  u32 offA[4];
#pragma unroll
  for (int j = 0; j < 4; ++j) {
    int r = w * 32 + j * 8 + (l >> 3);
    int idx = row0 + r;
    int entry = list[off_e + (idx < n_e ? idx : 0)];
    offA[j] = (u32)(entry >> 1) * DIM + schunk;
  }
  u32 offB[2];
#pragma unroll
  for (int j = 0; j < 2; ++j) {
    int r = w * 16 + j * 8 + (l >> 3);
    offB[j] = (u32)(tn * 128 + r) * DIM + schunk;
  }

#define STAGE1(buf, kt) do { u32 kof_ = (u32)(kt) * 64;                        \
    _Pragma("unroll")                                                          \
    for (int j = 0; j < 4; ++j) GLD16(Xb + offA[j] + kof_, &As[buf][w * 2048 + j * 512]); \
    _Pragma("unroll")                                                          \
    for (int j = 0; j < 2; ++j) {                                              \
      GLD16(W1e + offB[j] + kof_, &B1s[buf][w * 1024 + j * 512]);              \
      GLD16(W2e + offB[j] + kof_, &B2s[buf][w * 1024 + j * 512]);              \
    } } while (0)

  f32x4 acc1[4][4], acc2[4][4];
#pragma unroll
  for (int mi = 0; mi < 4; ++mi)
#pragma unroll
    for (int ni = 0; ni < 4; ++ni) {
      acc1[mi][ni] = (f32x4){0.f, 0.f, 0.f, 0.f};
      acc2[mi][ni] = (f32x4){0.f, 0.f, 0.f, 0.f};
    }
  int wm = w >> 1, wn = w & 1;

  STAGE1(0, 0);
  STAGE1(1, 1);
  for (int kt = 0; kt < DIM / 64; ++kt) {
    if (kt < DIM / 64 - 1) { WAITV(8); } else { WAITV(0); }
    __builtin_amdgcn_s_barrier();
    int cur = kt & 1;
    const u16* Ab  = As[cur];
    const u16* B1b = B1s[cur];
    const u16* B2b = B2s[cur];
#pragma unroll
    for (int ks = 0; ks < 2; ++ks) {
      bf16x8 a[4], b1[4], b2[4];
#pragma unroll
      for (int mi = 0; mi < 4; ++mi)
        a[mi] = *lds_frag(Ab, wm * 64 + mi * 16 + (l & 15), ks * 4 + (l >> 4));
#pragma unroll
      for (int ni = 0; ni < 4; ++ni) {
        b1[ni] = *lds_frag(B1b, wn * 64 + ni * 16 + (l & 15), ks * 4 + (l >> 4));
        b2[ni] = *lds_frag(B2b, wn * 64 + ni * 16 + (l & 15), ks * 4 + (l >> 4));
      }
#pragma unroll
      for (int mi = 0; mi < 4; ++mi)
#pragma unroll
        for (int ni = 0; ni < 4; ++ni) {
          acc1[mi][ni] = __builtin_amdgcn_mfma_f32_16x16x32_bf16(a[mi], b1[ni], acc1[mi][ni], 0, 0, 0);
          acc2[mi][ni] = __builtin_amdgcn_mfma_f32_16x16x32_bf16(a[mi], b2[ni], acc2[mi][ni], 0, 0, 0);
        }
    }
    asm volatile("" ::: "memory");
    __builtin_amdgcn_s_barrier();
    if (kt + 2 < DIM / 64) STAGE1(cur, kt + 2);
  }

#pragma unroll
  for (int mi = 0; mi < 4; ++mi) {
#pragma unroll
    for (int i = 0; i < 4; ++i) {
      int m_loc = wm * 64 + mi * 16 + (l >> 4) * 4 + i;
      int idx = row0 + m_loc;
      if (idx < n_e) {
        size_t pos = (size_t)(off_e + idx);
#pragma unroll
        for (int ni = 0; ni < 4; ++ni) {
          int h_loc = tn * 128 + wn * 64 + ni * 16 + (l & 15);
          float h1 = acc1[mi][ni][i];
          float h2 = acc2[mi][ni][i];
          float hv = h1 / (1.f + __expf(-h1)) * h2;
          hidden[pos * HID + h_loc] = f2bf(hv);
        }
      }
    }
  }
#undef STAGE1
}

// ---------------- GEMM2: eout = hidden . W3^T (unscaled bf16) ----------------
// tn FASTEST within XCD chunk (same locality rationale as gemm1).
__global__ __launch_bounds__(256, 2) void gemm2_kernel(
    const u16* __restrict__ hidden, const u16* __restrict__ W3b,
    const int* __restrict__ offs, const int* __restrict__ counts,
    const int* __restrict__ tileE, const int* __restrict__ tileRow,
    const int* __restrict__ n_tiles, u16* __restrict__ eout) {
  int flat = blockIdx.x + MAXT2 * blockIdx.y;
  int nf = (flat & 7) * (MAXT2 * (DIM / 128) / 8) + (flat >> 3);
  int bx = nf >> 3;          // row-tile: SLOW index
  int tn = nf & 7;           // col-tile: FAST index
  if (bx >= *n_tiles) return;
  int e = tileE[bx], row0 = tileRow[bx];
  int n_e = counts[e], off_e = offs[e];
  __shared__ u16 As[2][128 * 64];
  __shared__ u16 Bs[2][128 * 64];
  int tid = threadIdx.x, w = tid >> 6, l = tid & 63;
  const u16* W3e = W3b + (size_t)e * DIM * HID;

  int schunk = ((l & 7) ^ (l >> 3)) * 8;
  u32 offA[4], offB[4];
#pragma unroll
  for (int j = 0; j < 4; ++j) {
    int r = w * 32 + j * 8 + (l >> 3);
    int idx = row0 + r;
    int pos = off_e + (idx < n_e ? idx : 0);
    offA[j] = (u32)pos * HID + schunk;
    offB[j] = (u32)(tn * 128 + r) * HID + schunk;
  }

#define STAGE2(buf, kt) do { u32 kof_ = (u32)(kt) * 64;                        \
    _Pragma("unroll")                                                          \
    for (int j = 0; j < 4; ++j) {                                              \
      GLD16(hidden + offA[j] + kof_, &As[buf][w * 2048 + j * 512]);            \
      GLD16(W3e    + offB[j] + kof_, &Bs[buf][w * 2048 + j * 512]);            \
    } } while (0)

  f32x4 acc[4][4];
#pragma unroll
  for (int mi = 0; mi < 4; ++mi)
#pragma unroll
    for (int ni = 0; ni < 4; ++ni) acc[mi][ni] = (f32x4){0.f, 0.f, 0.f, 0.f};
  int wm = w >> 1, wn = w & 1;

  STAGE2(0, 0);
  STAGE2(1, 1);
  for (int kt = 0; kt < HID / 64; ++kt) {
    if (kt < HID / 64 - 1) { WAITV(8); } else { WAITV(0); }
    __builtin_amdgcn_s_barrier();
    int cur = kt & 1;
    const u16* Ab = As[cur];
    const u16* Bb = Bs[cur];
#pragma unroll
    for (int ks = 0; ks < 2; ++ks) {
      bf16x8 a[4], b[4];
#pragma unroll
      for (int mi = 0; mi < 4; ++mi)
        a[mi] = *lds_frag(Ab, wm * 64 + mi * 16 + (l & 15), ks * 4 + (l >> 4));
#pragma unroll
      for (int ni = 0; ni < 4; ++ni)
        b[ni] = *lds_frag(Bb, wn * 64 + ni * 16 + (l & 15), ks * 4 + (l >> 4));
#pragma unroll
      for (int mi = 0; mi < 4; ++mi)
#pragma unroll
        for (int ni = 0; ni < 4; ++ni)
          acc[mi][ni] = __builtin_amdgcn_mfma_f32_16x16x32_bf16(a[mi], b[ni], acc[mi][ni], 0, 0, 0);
    }
    asm volatile("" ::: "memory");
    __builtin_amdgcn_s_barrier();
    if (kt + 2 < HID / 64) STAGE2(cur, kt + 2);
  }

#pragma unroll
  for (int mi = 0; mi < 4; ++mi) {
#pragma unroll
    for (int i = 0; i < 4; ++i) {
      int m_loc = wm * 64 + mi * 16 + (l >> 4) * 4 + i;
      int idx = row0 + m_loc;
      if (idx < n_e) {
        size_t pos = (size_t)(off_e + idx);
#pragma unroll
        for (int ni = 0; ni < 4; ++ni) {
          int d_loc = tn * 128 + wn * 64 + ni * 16 + (l & 15);
          eout[pos * DIM + d_loc] = f2bf(acc[mi][ni][i]);
        }
      }
    }
  }
#undef STAGE2
}

// ---------------- combine: out[t] = p0*eout[pos0] + p1*eout[pos1] ----------
__global__ __launch_bounds__(256) void combine_kernel(
    const u16* __restrict__ eout, const int* __restrict__ pos_of,
    const float* __restrict__ gate_prob, float* __restrict__ out) {
  int gid = blockIdx.x * 256 + threadIdx.x;   // NTOK*128 threads
  int t = gid >> 7, dq = (gid & 127) * 8;
  int p0 = pos_of[t * 2], p1 = pos_of[t * 2 + 1];
  float w0 = gate_prob[t * 2], w1 = gate_prob[t * 2 + 1];
  bf16x8 e0 = *(const bf16x8*)&eout[(size_t)p0 * DIM + dq];
  bf16x8 e1 = *(const bf16x8*)&eout[(size_t)p1 * DIM + dq];
  float4 o0, o1;
  o0.x = w0 * bf2f(e0[0]) + w1 * bf2f(e1[0]);
  o0.y = w0 * bf2f(e0[1]) + w1 * bf2f(e1[1]);
  o0.z = w0 * bf2f(e0[2]) + w1 * bf2f(e1[2]);
  o0.w = w0 * bf2f(e0[3]) + w1 * bf2f(e1[3]);
  o1.x = w0 * bf2f(e0[4]) + w1 * bf2f(e1[4]);
  o1.y = w0 * bf2f(e0[5]) + w1 * bf2f(e1[5]);
  o1.z = w0 * bf2f(e0[6]) + w1 * bf2f(e1[6]);
  o1.w = w0 * bf2f(e0[7]) + w1 * bf2f(e1[7]);
  float4* op = (float4*)&out[(size_t)t * DIM + dq];
  op[0] = o0; op[1] = o1;
}

// ---------------- launch ----------------
extern "C" void kernel_launch(void* const* d_in, const int* in_sizes, int n_in,
                              void* d_out, int out_size, void* d_ws, size_t ws_size,
                              hipStream_t stream) {
  const float* x  = (const float*)d_in[0];
  const float* Wg = (const float*)d_in[1];
  const float* W1 = (const float*)d_in[2];
  const float* W2 = (const float*)d_in[3];
  const float* W3 = (const float*)d_in[4];
  float* out = (float*)d_out;

  char* wsb = (char*)d_ws;
  int*   counts    = (int*)(wsb + 0);
  int*   cursors   = (int*)(wsb + 64);
  int*   offs      = (int*)(wsb + 128);
  int*   nt1       = (int*)(wsb + 192);
  int*   nt2       = (int*)(wsb + 196);
  int*   tileE1    = (int*)(wsb + 512);
  int*   tileRow1  = (int*)(wsb + 1024);
  int*   tileE2    = (int*)(wsb + 1536);
  int*   tileRow2  = (int*)(wsb + 2560);
  int*   gate_idx  = (int*)(wsb + 4096);
  float* gate_prob = (float*)(wsb + 4096 + 65536);
  int*   pos_of    = (int*)(wsb + 4096 + 2 * 65536);
  int*   list      = (int*)(wsb + 4096 + 3 * 65536);
  u16* Xb     = (u16*)(wsb + (1 << 20));
  u16* W1b    = Xb  + (size_t)NTOK * DIM;
  u16* W2b    = W1b + (size_t)NEXP * HID * DIM;
  u16* W3b    = W2b + (size_t)NEXP * HID * DIM;
  u16* hidden = W3b + (size_t)NEXP * DIM * HID;   // [2*NTOK][HID]
  u16* eout   = W1b;   // W1b/W2b dead after gemm1

  hipMemsetAsync(wsb, 0, 256, stream);

  convert3_kernel<<<4096, 256, 0, stream>>>(
      (const float4*)W1, (const float4*)W2, (const float4*)W3,
      (ushort4*)W1b, (ushort4*)W2b, (ushort4*)W3b);

  gating_kernel<<<NTOK / 4, 256, 0, stream>>>(
      (const float4*)x, (const float4*)Wg, gate_idx, gate_prob, Xb);
  hist_kernel<<<NTOK * 2 / 256, 256, 0, stream>>>(gate_idx, counts);
  scan_kernel<<<1, 64, 0, stream>>>(counts, offs, cursors,
                                    tileE1, tileRow1, nt1, tileE2, tileRow2, nt2);
  scatter_kernel<<<NTOK * 2 / 256, 256, 0, stream>>>(gate_idx, cursors, list, pos_of);

  gemm1_kernel<<<dim3(MAXT1, HID / 128), 512, 0, stream>>>(
      Xb, W1b, W2b, list, offs, counts, tileE1, tileRow1, nt1, hidden);
  gemm2_kernel<<<dim3(MAXT2, DIM / 128), 256, 0, stream>>>(
      hidden, W3b, offs, counts, tileE2, tileRow2, nt2, eout);
  combine_kernel<<<NTOK * 128 / 256, 256, 0, stream>>>(eout, pos_of, gate_prob, out);
}